// Round 8
// baseline (35.685 us; speedup 1.0000x reference)
//
#include <hip/hip_runtime.h>

// BilinearSampler: image (B,H,W,C) f32, grid (B,H,W,2) f32 -> out (B,H,W,C) f32
// B=16, H=256, W=256, C=32.
//
// R7: PX=8 outstanding-loads probe. 32 in-flight 16B gathers per wave
// (128 VGPR of load destinations). Occupancy-weighted outstanding/SIMD
// rises ~1.6x vs PX=4 (both R3/R4 configs delivered ~50/SIMD - flat result
// didn't discriminate). Keeps R6 per-XCD batch schedule + NT stores +
// temporal grid loads. Weights recomputed AFTER gather issue (lean VGPR).

constexpr int Bn = 16, Hn = 256, Wn = 256, Cn = 32;
constexpr int PX = 8;   // pixels per thread

typedef float f32x2 __attribute__((ext_vector_type(2)));
typedef float f32x4 __attribute__((ext_vector_type(4)));

__global__ __launch_bounds__(256) void BilinearSampler_29300266893747_kernel(
    const float* __restrict__ image,
    const float* __restrict__ grid,
    float* __restrict__ out)
{
    // 4096 blocks, 256 blocks per batch, XCD(bid) = bid % 8 (round-robin).
    // epoch 0 (bid < 2048): XCD k -> batch k.  epoch 1: XCD k -> batch k+8.
    const unsigned bid   = blockIdx.x;
    const unsigned epoch = bid >> 11;          // 0 or 1
    const unsigned r     = bid & 2047u;
    const unsigned wid   = (epoch << 11) + (r & 7u) * 256u + (r >> 3);

    const int tid = threadIdx.x;
    const int q   = tid & 7;        // channel quad: channels q*4..q*4+3
    const int s   = tid >> 3;       // pixel slot in [0,32)
    const int co  = q * 4;

    const long long base = (long long)wid * (32 * PX);  // 256 pixels per block
    const int b = (int)(base >> 16);   // 65536 % 256 == 0: no batch straddle
    const float* img_b = image + (long long)b * Hn * Wn * Cn;
    const long long p0 = base + s;     // pixel i is p0 + 32*i

    // ---- grid coords (temporal; coalesced across block) ----
    f32x2 g[PX];
#pragma unroll
    for (int i = 0; i < PX; ++i) g[i] = *((const f32x2*)grid + (p0 + 32 * i));

    // ---- minimal address math, then issue ALL 32 gathers ----
    f32x4 Ia[PX], Ib[PX], Ic[PX], Id[PX];
#pragma unroll
    for (int i = 0; i < PX; ++i) {
        const float x = (g[i].x + 1.0f) * 255.0f * 0.5f;
        const float y = (g[i].y + 1.0f) * 255.0f * 0.5f;
        const int x0 = (int)floorf(x), y0 = (int)floorf(y);
        const int x0c = min(max(x0,     0), Wn - 1);
        const int x1c = min(max(x0 + 1, 0), Wn - 1);
        const int y0c = min(max(y0,     0), Hn - 1);
        const int y1c = min(max(y0 + 1, 0), Hn - 1);
        // element offsets within batch: (y*256 + x)*32 + co
        const int oa = (y0c << 13) + (x0c << 5) + co;
        const int oc = (y0c << 13) + (x1c << 5) + co;
        const int ob = (y1c << 13) + (x0c << 5) + co;
        const int od = (y1c << 13) + (x1c << 5) + co;
        Ia[i] = *(const f32x4*)(img_b + oa);
        Ib[i] = *(const f32x4*)(img_b + ob);
        Ic[i] = *(const f32x4*)(img_b + oc);
        Id[i] = *(const f32x4*)(img_b + od);
    }

    // ---- recompute weights (cheap VALU, saves 8 regs/px), blend, NT store ----
#pragma unroll
    for (int i = 0; i < PX; ++i) {
        const float x = (g[i].x + 1.0f) * 255.0f * 0.5f;
        const float y = (g[i].y + 1.0f) * 255.0f * 0.5f;
        const int x0 = (int)floorf(x), y0 = (int)floorf(y);
        const int x0c = min(max(x0,     0), Wn - 1);
        const int x1c = min(max(x0 + 1, 0), Wn - 1);
        const int y0c = min(max(y0,     0), Hn - 1);
        const int y1c = min(max(y0 + 1, 0), Hn - 1);
        const float x0f = (float)x0c, x1f = (float)x1c;
        const float y0f = (float)y0c, y1f = (float)y1c;
        const float wa = (x1f - x) * (y1f - y);
        const float wb = (x1f - x) * (y - y0f);
        const float wc = (x - x0f) * (y1f - y);
        const float wd = (x - x0f) * (y - y0f);

        const f32x4 o = wa * Ia[i] + wb * Ib[i] + wc * Ic[i] + wd * Id[i];
        __builtin_nontemporal_store(o, (f32x4*)(out + (p0 + 32 * i) * Cn + co));
    }
}

extern "C" void kernel_launch(void* const* d_in, const int* in_sizes, int n_in,
                              void* d_out, int out_size, void* d_ws, size_t ws_size,
                              hipStream_t stream) {
    const float* image = (const float*)d_in[0];
    const float* grid  = (const float*)d_in[1];
    float* out = (float*)d_out;

    const long long total = (long long)Bn * Hn * Wn * 8 / PX;  // 1,048,576 threads
    const int block = 256;
    const int nblocks = (int)((total + block - 1) / block);    // 4096

    BilinearSampler_29300266893747_kernel<<<nblocks, block, 0, stream>>>(image, grid, out);
}